// Round 7
// baseline (679.873 us; speedup 1.0000x reference)
//
#include <hip/hip_runtime.h>
#include <hip/hip_bf16.h>

// LSTM: B=512, T=512, I=128, H=50, O=10, fp32.
// R7: (1) dot reverted to R5's known-correct fmaf/f16-convert form (R6's asm
// v_dot2_f32_f16 is the prime suspect for the 4.4e-2 failure). (2) keep R6's
// xp [b][t][g] relayout (xproj contiguous, lstm streams 400B/step). (3) lstm
// split across 2 waves/batch: wave0 = i,f gates; wave1 = g,o + c/h tail.
// Halves per-wave issue and doubles waves/CU (2->4) to hide ds/xp latency.

#define BB 512
#define TT 512
#define II 128
#define HH 50
#define GG 200   // 4*H

typedef _Float16 half2v __attribute__((ext_vector_type(2)));
typedef _Float16 half4v __attribute__((ext_vector_type(4)));
typedef _Float16 half8v __attribute__((ext_vector_type(8)));
typedef float float4v __attribute__((ext_vector_type(4)));

__device__ __forceinline__ float dot2f(half2v a, half2v b, float c) {
    // known-correct (R5): fpext + fma
    return fmaf((float)a[1], (float)b[1], fmaf((float)a[0], (float)b[0], c));
}

__device__ __forceinline__ float fsig(float x) {
    return 1.f / (1.f + __expf(-x));
}
__device__ __forceinline__ float ftanh(float x) {
    return 2.f * fsig(2.f * x) - 1.f;
}

// ---------------- Kernel 0: prep (once per launch) ----------------
// wfrags: W_ih as f16 MFMA B-fragments [nt 13][kc 4][lane 64][j 8]
// whh16:  W_hh rows padded to 56 f16   [g 200][56]
// biasv:  b_ih + b_hh                  [g 200]
__global__ __launch_bounds__(256) void prep_kernel(
    const float* __restrict__ W_ih, const float* __restrict__ W_hh,
    const float* __restrict__ b_ih, const float* __restrict__ b_hh,
    _Float16* __restrict__ wfrags, _Float16* __restrict__ whh16,
    float* __restrict__ biasv)
{
    int idx = blockIdx.x * 256 + threadIdx.x;
    if (idx < 3328) {                       // 13*4*64 fragment slots
        int lane = idx & 63, kc = (idx >> 6) & 3, nt = idx >> 8;
        int g = nt * 16 + (lane & 15);
        int k0 = kc * 32 + ((lane >> 4) & 3) * 8;
        half8v v;
        #pragma unroll
        for (int j = 0; j < 8; ++j)
            v[j] = (g < GG) ? (_Float16)W_ih[g * II + k0 + j] : (_Float16)0.f;
        *(half8v*)(wfrags + (size_t)idx * 8) = v;
    } else if (idx < 3328 + 2800) {         // 200 rows * 14 quads
        int r = idx - 3328;
        int g = r / 14, j4 = r % 14;
        #pragma unroll
        for (int j = 0; j < 4; ++j) {
            int hidx = j4 * 4 + j;
            whh16[g * 56 + hidx] = (hidx < HH) ? (_Float16)W_hh[g * HH + hidx]
                                               : (_Float16)0.f;
        }
    } else if (idx < 3328 + 2800 + GG) {
        int g = idx - 6128;
        biasv[g] = b_ih[g] + b_hh[g];
    }
}

// ---------------- Kernel 1: xproj via MFMA ----------------
// Block: 256 thr, tile = 64 rows of (b fixed, t consecutive). x read and xp
// write are each one contiguous span per block. xp layout: [b][tl][g] f16.
#define EPIW 216
__global__ __launch_bounds__(256) void xproj_mfma(
    const float* __restrict__ x, const _Float16* __restrict__ wfrags,
    _Float16* __restrict__ xp16, int t0, int Tc)
{
    __shared__ __align__(16) _Float16 smem[64 * EPIW];  // 27.6 KB
    const int tid = threadIdx.x;
    const int row0 = blockIdx.x * 64;       // row = b*Tc + tl ; 64 | Tc
    const int b = row0 / Tc;
    const int tl0 = row0 - b * Tc;

    // --- Stage A into fragment order (first 8192 halfs of smem) ---
    const float* xbase = x + ((size_t)b * TT + (t0 + tl0)) * II;
    #pragma unroll
    for (int it = 0; it < 8; ++it) {
        int d = it * 512 + tid * 2;
        int lane = (d >> 2) & 63, kc = (d >> 8) & 3, wr = d >> 10;
        int jd = d & 3;                      // 0 or 2
        int row = wr * 16 + (lane & 15);     // M index = t offset
        int k0 = kc * 32 + ((lane >> 4) & 3) * 8 + jd * 2;
        const float4 v = *(const float4*)(xbase + (size_t)row * II + k0);
        half4v p = { (_Float16)v.x, (_Float16)v.y, (_Float16)v.z, (_Float16)v.w };
        *(half4v*)(smem + d * 2) = p;
    }
    __syncthreads();

    const int w = tid >> 6;
    const int l = tid & 63;

    half8v areg[4];
    #pragma unroll
    for (int kc = 0; kc < 4; ++kc)
        areg[kc] = *(half8v*)(smem + (((w * 4 + kc) * 64) + l) * 8);

    float4v acc[13];
    #pragma unroll
    for (int nt = 0; nt < 13; ++nt) acc[nt] = (float4v){0.f, 0.f, 0.f, 0.f};

    #pragma unroll
    for (int kc = 0; kc < 4; ++kc) {
        #pragma unroll
        for (int nt = 0; nt < 13; ++nt) {
            half8v bf = *(const half8v*)(wfrags + (size_t)(((nt * 4 + kc) * 64) + l) * 8);
            acc[nt] = __builtin_amdgcn_mfma_f32_16x16x32_f16(areg[kc], bf, acc[nt], 0, 0, 0);
        }
    }
    __syncthreads();   // smem reused for epilogue

    // --- C tile to LDS [row][g] ---
    const int colb = l & 15, rquad = l >> 4;
    #pragma unroll
    for (int nt = 0; nt < 13; ++nt) {
        int g = nt * 16 + colb;
        if (g < GG) {
            #pragma unroll
            for (int reg = 0; reg < 4; ++reg) {
                int row = w * 16 + rquad * 4 + reg;
                smem[row * EPIW + g] = (_Float16)acc[nt][reg];
            }
        }
    }
    __syncthreads();

    // --- Coalesced copy: 64 rows x 200 halfs = 6400 dwords contiguous ---
    uint32_t* xpw = (uint32_t*)(xp16 + (size_t)row0 * GG);
    #pragma unroll
    for (int kkk = 0; kkk < 25; ++kkk) {
        int d = tid + kkk * 256;
        int row = d / 100;
        int off = d - row * 100;
        uint32_t v = *(const uint32_t*)(smem + row * EPIW + off * 2);
        xpw[d] = v;
    }
}

// ---------------- Kernel 2: recurrence (2 waves per batch) ----------------
// 128 thr/block. wave0 thread k: gate rows k (i), k+50 (f).
// wave1 thread k: rows k+100 (g), k+150 (o) + owns c_k and the h update.
// i,f passed wave0->wave1 via f32 LDS. h broadcast f16 (7 b128/wave/step).
__global__ __launch_bounds__(128, 2) void lstm_rec(
    const _Float16* __restrict__ xp16, const _Float16* __restrict__ whh16,
    const float* __restrict__ biasv,
    float* __restrict__ hs, float* __restrict__ cs, int Tc, int first)
{
    __shared__ __align__(16) _Float16 hbuf[2][64];
    __shared__ __align__(16) float actI[64];
    __shared__ __align__(16) float actF[64];
    const int b = blockIdx.x;
    const int tid = threadIdx.x;
    const int wid = tid >> 6;
    const int k = tid & 63;
    const int kk = (k < HH) ? k : 0;

    const int rA = kk + wid * 100;        // w0: i-row k   ; w1: g-row k+100
    const int rB = kk + 50 + wid * 100;   // w0: f-row k+50; w1: o-row k+150

    half8v wA[7], wB[7];
    #pragma unroll
    for (int j = 0; j < 7; ++j) {
        wA[j] = *(const half8v*)(whh16 + (size_t)rA * 56 + j * 8);
        wB[j] = *(const half8v*)(whh16 + (size_t)rB * 56 + j * 8);
    }
    const float bA = biasv[rA], bB = biasv[rB];

    float c = 0.f;
    if (wid == 1 && !first && k < HH) c = cs[b * HH + kk];
    if (wid == 0) {
        hbuf[0][k] = (_Float16)0.f;
        hbuf[1][k] = (_Float16)0.f;
        if (!first && k < HH) hbuf[0][k] = (_Float16)hs[b * HH + k];
    }
    __syncthreads();

    const _Float16* xpb = xp16 + (size_t)b * Tc * GG;   // stream, +GG per step

    _Float16 pA[4], pB[4];
    #pragma unroll
    for (int d = 0; d < 4; ++d) {
        int td = (d < Tc) ? d : (Tc - 1);
        const _Float16* xn = xpb + (size_t)td * GG;
        pA[d] = xn[rA]; pB[d] = xn[rB];
    }

    float hlast = 0.f;
    #pragma unroll 4
    for (int t = 0; t < Tc; ++t) {
        const int s = t & 3;
        const int cur = t & 1;
        float aA0 = (float)pA[s] + bA, aA1 = 0.f;
        float aB0 = (float)pB[s] + bB, aB1 = 0.f;

        // refill slot s for t+4
        {
            int tn = t + 4; if (tn >= Tc) tn = Tc - 1;
            const _Float16* xn = xpb + (size_t)tn * GG;
            pA[s] = xn[rA]; pB[s] = xn[rB];
        }

        half8v hv[7];
        #pragma unroll
        for (int j = 0; j < 7; ++j) hv[j] = *(half8v*)(hbuf[cur] + j * 8);

        #pragma unroll
        for (int j = 0; j < 7; ++j) {
            half2v* hp = (half2v*)&hv[j];
            #pragma unroll
            for (int q = 0; q < 4; ++q) {
                half2v hq = hp[q];
                if (((j * 4 + q) & 1) == 0) {
                    aA0 = dot2f(hq, ((half2v*)&wA[j])[q], aA0);
                    aB0 = dot2f(hq, ((half2v*)&wB[j])[q], aB0);
                } else {
                    aA1 = dot2f(hq, ((half2v*)&wA[j])[q], aA1);
                    aB1 = dot2f(hq, ((half2v*)&wB[j])[q], aB1);
                }
            }
        }

        if (wid == 0 && k < HH) {
            actI[k] = fsig(aA0 + aA1);      // i-gate
            actF[k] = fsig(aB0 + aB1);      // f-gate
        }
        __syncthreads();
        if (wid == 1 && k < HH) {
            float ig = actI[k], fg = actF[k];
            float gg = ftanh(aA0 + aA1);    // g-gate
            float oo = fsig(aB0 + aB1);     // o-gate
            c = fg * c + ig * gg;
            float hn = oo * ftanh(c);
            hbuf[cur ^ 1][k] = (_Float16)hn;
            hlast = hn;
        }
        __syncthreads();
    }
    if (wid == 1 && k < HH) {
        hs[b * HH + k] = hlast;
        cs[b * HH + k] = c;
    }
}

// ---------------- Kernel 3: FC epilogue ----------------
__global__ __launch_bounds__(256) void fc_kernel(
    const float* __restrict__ hs, const float* __restrict__ W_fc,
    const float* __restrict__ b_fc, float* __restrict__ out)
{
    int idx = blockIdx.x * blockDim.x + threadIdx.x;   // 512*10
    if (idx < BB * 10) {
        int b = idx / 10, o = idx % 10;
        float a = b_fc[o];
        #pragma unroll
        for (int kx = 0; kx < HH; ++kx)
            a += hs[b * HH + kx] * W_fc[o * HH + kx];
        out[idx] = a;
    }
}

extern "C" void kernel_launch(void* const* d_in, const int* in_sizes, int n_in,
                              void* d_out, int out_size, void* d_ws, size_t ws_size,
                              hipStream_t stream)
{
    const float* x    = (const float*)d_in[0];
    const float* W_ih = (const float*)d_in[1];
    const float* W_hh = (const float*)d_in[2];
    const float* b_ih = (const float*)d_in[3];
    const float* b_hh = (const float*)d_in[4];
    const float* W_fc = (const float*)d_in[5];
    const float* b_fc = (const float*)d_in[6];
    float* out = (float*)d_out;
    char* wsb = (char*)d_ws;

    const size_t hs_b = (size_t)BB * HH * sizeof(float);        // 102400
    const size_t wfrags_b = (size_t)13 * 4 * 64 * 8 * 2;        // 53248
    const size_t whh_b = (size_t)GG * 56 * 2;                   // 22400
    const size_t bias_b = 1024;
    const size_t fixed_b = 2 * hs_b + wfrags_b + whh_b + bias_b;

    int Tc = TT;
    while (Tc > 64 && (size_t)BB * Tc * GG * 2 + fixed_b > ws_size)
        Tc >>= 1;

    _Float16* xp16 = (_Float16*)wsb;
    char* p = wsb + (size_t)BB * Tc * GG * 2;
    float* hsbuf = (float*)p;            p += hs_b;
    float* csbuf = (float*)p;            p += hs_b;
    _Float16* wfrags = (_Float16*)p;     p += wfrags_b;
    _Float16* whh16 = (_Float16*)p;      p += whh_b;
    float* biasv = (float*)p;

    prep_kernel<<<25, 256, 0, stream>>>(W_ih, W_hh, b_ih, b_hh, wfrags, whh16, biasv);

    const int nch = TT / Tc;
    for (int j = 0; j < nch; ++j) {
        xproj_mfma<<<(BB * Tc) / 64, 256, 0, stream>>>(x, wfrags, xp16, j * Tc, Tc);
        lstm_rec<<<BB, 128, 0, stream>>>(xp16, whh16, biasv, hsbuf, csbuf, Tc, j == 0);
    }
    fc_kernel<<<(BB * 10 + 255) / 256, 256, 0, stream>>>(hsbuf, W_fc, b_fc, out);
}

// Round 8
// 545.944 us; speedup vs baseline: 1.2453x; 1.2453x over previous
//
#include <hip/hip_runtime.h>
#include <hip/hip_bf16.h>

// LSTM: B=512, T=512, I=128, H=50, O=10, fp32.
// R8: (1) lstm_rec back to single-wave 64-thr blocks (R7's 2-wave split cost
// ~700 cyc/step in cross-wave barriers). Inner dot via _Float16x2 vector
// arithmetic -> v_pk_fma_f16 (2 MAC/inst): 112 pk_fma/step vs ~475 unfused
// cvt+fma. f16 accumulation in 4 short chains/gate, reduced in f32.
// (2) xproj: A-fragments loaded directly from x (no LDS staging round-trip);
// one barrier per block instead of four. NOTE: v_dot2_f32_f16 asm = R6's
// correctness bug; gfx950 ISA doc omits it — do not use.

#define BB 512
#define TT 512
#define II 128
#define HH 50
#define GG 200   // 4*H

typedef _Float16 half2v __attribute__((ext_vector_type(2)));
typedef _Float16 half4v __attribute__((ext_vector_type(4)));
typedef _Float16 half8v __attribute__((ext_vector_type(8)));
typedef float float4v __attribute__((ext_vector_type(4)));

__device__ __forceinline__ float fsig(float x) {
    return 1.f / (1.f + __expf(-x));
}
__device__ __forceinline__ float ftanh(float x) {
    return 2.f * fsig(2.f * x) - 1.f;
}

// ---------------- Kernel 0: prep (once per launch) ----------------
// wfrags: W_ih as f16 MFMA B-fragments [nt 13][kc 4][lane 64][j 8]
// whh16:  W_hh rows padded to 56 f16   [g 200][56]
// biasv:  b_ih + b_hh                  [g 200]
__global__ __launch_bounds__(256) void prep_kernel(
    const float* __restrict__ W_ih, const float* __restrict__ W_hh,
    const float* __restrict__ b_ih, const float* __restrict__ b_hh,
    _Float16* __restrict__ wfrags, _Float16* __restrict__ whh16,
    float* __restrict__ biasv)
{
    int idx = blockIdx.x * 256 + threadIdx.x;
    if (idx < 3328) {                       // 13*4*64 fragment slots
        int lane = idx & 63, kc = (idx >> 6) & 3, nt = idx >> 8;
        int g = nt * 16 + (lane & 15);
        int k0 = kc * 32 + ((lane >> 4) & 3) * 8;
        half8v v;
        #pragma unroll
        for (int j = 0; j < 8; ++j)
            v[j] = (g < GG) ? (_Float16)W_ih[g * II + k0 + j] : (_Float16)0.f;
        *(half8v*)(wfrags + (size_t)idx * 8) = v;
    } else if (idx < 3328 + 2800) {         // 200 rows * 14 quads
        int r = idx - 3328;
        int g = r / 14, j4 = r % 14;
        #pragma unroll
        for (int j = 0; j < 4; ++j) {
            int hidx = j4 * 4 + j;
            whh16[g * 56 + hidx] = (hidx < HH) ? (_Float16)W_hh[g * HH + hidx]
                                               : (_Float16)0.f;
        }
    } else if (idx < 3328 + 2800 + GG) {
        int g = idx - 6128;
        biasv[g] = b_ih[g] + b_hh[g];
    }
}

// ---------------- Kernel 1: xproj via MFMA ----------------
// Block: 256 thr, tile = 64 rows (b fixed, t consecutive). A-fragments read
// directly from x (no staging). xp layout: [b][tl][g] f16. One barrier.
#define EPIW 216
__global__ __launch_bounds__(256) void xproj_mfma(
    const float* __restrict__ x, const _Float16* __restrict__ wfrags,
    _Float16* __restrict__ xp16, int t0, int Tc)
{
    __shared__ __align__(16) _Float16 smem[64 * EPIW];  // epilogue only, 27.6 KB
    const int tid = threadIdx.x;
    const int row0 = blockIdx.x * 64;       // row = b*Tc + tl ; 64 | Tc
    const int b = row0 / Tc;
    const int tl0 = row0 - b * Tc;
    const int w = tid >> 6;
    const int l = tid & 63;
    const int mrow = w * 16 + (l & 15);     // local row 0..63 (t offset)
    const int quad = (l >> 4) & 3;

    // --- A fragments straight from x: lane l row mrow, k = kc*32+quad*8+j ---
    const float* xrow = x + ((size_t)b * TT + (t0 + tl0 + mrow)) * II;
    half8v areg[4];
    #pragma unroll
    for (int kc = 0; kc < 4; ++kc) {
        int k0 = kc * 32 + quad * 8;
        float4 v0 = *(const float4*)(xrow + k0);
        float4 v1 = *(const float4*)(xrow + k0 + 4);
        half8v a = { (_Float16)v0.x, (_Float16)v0.y, (_Float16)v0.z, (_Float16)v0.w,
                     (_Float16)v1.x, (_Float16)v1.y, (_Float16)v1.z, (_Float16)v1.w };
        areg[kc] = a;
    }

    float4v acc[13];
    #pragma unroll
    for (int nt = 0; nt < 13; ++nt) acc[nt] = (float4v){0.f, 0.f, 0.f, 0.f};

    #pragma unroll
    for (int kc = 0; kc < 4; ++kc) {
        #pragma unroll
        for (int nt = 0; nt < 13; ++nt) {
            half8v bf = *(const half8v*)(wfrags + (size_t)(((nt * 4 + kc) * 64) + l) * 8);
            acc[nt] = __builtin_amdgcn_mfma_f32_16x16x32_f16(areg[kc], bf, acc[nt], 0, 0, 0);
        }
    }

    // --- C tile to LDS [row][g] (waves write disjoint rows; no barrier) ---
    const int colb = l & 15, rquad = l >> 4;
    #pragma unroll
    for (int nt = 0; nt < 13; ++nt) {
        int g = nt * 16 + colb;
        if (g < GG) {
            #pragma unroll
            for (int reg = 0; reg < 4; ++reg) {
                int row = w * 16 + rquad * 4 + reg;
                smem[row * EPIW + g] = (_Float16)acc[nt][reg];
            }
        }
    }
    __syncthreads();

    // --- Coalesced copy: 64 rows x 200 halfs = 6400 dwords contiguous ---
    uint32_t* xpw = (uint32_t*)(xp16 + (size_t)row0 * GG);
    #pragma unroll
    for (int kkk = 0; kkk < 25; ++kkk) {
        int d = tid + kkk * 256;
        int row = d / 100;
        int off = d - row * 100;
        uint32_t v = *(const uint32_t*)(smem + row * EPIW + off * 2);
        xpw[d] = v;
    }
}

// ---------------- Kernel 2: recurrence (single wave per batch) ----------------
// Thread k<50 owns gate rows {k,k+50,k+100,k+150} as f16 in regs (112 VGPR).
// Dot via half2 vector FMA -> v_pk_fma_f16, 4 chains/gate, f32 reduce.
// h f16 in LDS dbuf; 4-deep circular xp prefetch; xp streamed [b][t][g].
__global__ __launch_bounds__(64, 1) void lstm_rec(
    const _Float16* __restrict__ xp16, const _Float16* __restrict__ whh16,
    const float* __restrict__ biasv,
    float* __restrict__ hs, float* __restrict__ cs, int Tc, int first)
{
#pragma clang fp contract(fast)
    __shared__ __align__(16) _Float16 hbuf[2][64];
    const int b = blockIdx.x;
    const int k = threadIdx.x;
    const int kk = (k < HH) ? k : 0;

    half8v wI[7], wF[7], wG[7], wO[7];
    #pragma unroll
    for (int j = 0; j < 7; ++j) {
        wI[j] = *(const half8v*)(whh16 + (size_t)(kk      ) * 56 + j * 8);
        wF[j] = *(const half8v*)(whh16 + (size_t)(kk +  50) * 56 + j * 8);
        wG[j] = *(const half8v*)(whh16 + (size_t)(kk + 100) * 56 + j * 8);
        wO[j] = *(const half8v*)(whh16 + (size_t)(kk + 150) * 56 + j * 8);
    }
    const float bi = biasv[kk], bf2 = biasv[kk + 50],
                bg = biasv[kk + 100], bo = biasv[kk + 150];

    float c = (!first && k < HH) ? cs[b * HH + kk] : 0.f;
    hbuf[0][k] = (_Float16)0.f;
    hbuf[1][k] = (_Float16)0.f;
    if (!first && k < HH) hbuf[0][k] = (_Float16)hs[b * HH + k];
    __syncthreads();

    const _Float16* xpb = xp16 + (size_t)b * Tc * GG;   // stream, +GG per step

    _Float16 pi[4], pf[4], pg[4], po[4];
    #pragma unroll
    for (int d = 0; d < 4; ++d) {
        int td = (d < Tc) ? d : (Tc - 1);
        const _Float16* xn = xpb + (size_t)td * GG;
        pi[d] = xn[kk]; pf[d] = xn[kk + 50]; pg[d] = xn[kk + 100]; po[d] = xn[kk + 150];
    }

    float hlast = 0.f;
    #pragma unroll 4
    for (int t = 0; t < Tc; ++t) {
        const int s = t & 3;
        const int cur = t & 1;
        float aI = (float)pi[s] + bi;
        float aF = (float)pf[s] + bf2;
        float aG = (float)pg[s] + bg;
        float aO = (float)po[s] + bo;

        // refill prefetch slot s for step t+4
        {
            int tn = t + 4; if (tn >= Tc) tn = Tc - 1;
            const _Float16* xn = xpb + (size_t)tn * GG;
            pi[s] = xn[kk]; pf[s] = xn[kk + 50];
            pg[s] = xn[kk + 100]; po[s] = xn[kk + 150];
        }

        half8v hv[7];
        #pragma unroll
        for (int j = 0; j < 7; ++j) hv[j] = *(half8v*)(hbuf[cur] + j * 8);

        // 4 independent f16 chains per gate -> v_pk_fma_f16
        half2v cI[4], cF[4], cG[4], cO[4];
        #pragma unroll
        for (int q = 0; q < 4; ++q) {
            cI[q] = (half2v)0; cF[q] = (half2v)0;
            cG[q] = (half2v)0; cO[q] = (half2v)0;
        }
        #pragma unroll
        for (int j = 0; j < 7; ++j) {
            const half2v* hp = (const half2v*)&hv[j];
            #pragma unroll
            for (int q = 0; q < 4; ++q) {
                half2v hq = hp[q];
                cI[q] = hq * ((const half2v*)&wI[j])[q] + cI[q];
                cF[q] = hq * ((const half2v*)&wF[j])[q] + cF[q];
                cG[q] = hq * ((const half2v*)&wG[j])[q] + cG[q];
                cO[q] = hq * ((const half2v*)&wO[j])[q] + cO[q];
            }
        }
        half2v rI = (cI[0] + cI[1]) + (cI[2] + cI[3]);
        half2v rF = (cF[0] + cF[1]) + (cF[2] + cF[3]);
        half2v rG = (cG[0] + cG[1]) + (cG[2] + cG[3]);
        half2v rO = (cO[0] + cO[1]) + (cO[2] + cO[3]);
        aI += (float)rI[0] + (float)rI[1];
        aF += (float)rF[0] + (float)rF[1];
        aG += (float)rG[0] + (float)rG[1];
        aO += (float)rO[0] + (float)rO[1];

        float ii = fsig(aI), ff = fsig(aF), gg = ftanh(aG), oo = fsig(aO);
        c = ff * c + ii * gg;
        float hn = oo * ftanh(c);
        if (k < HH) hbuf[cur ^ 1][k] = (_Float16)hn;
        __syncthreads();                    // single wave: near-free
        hlast = hn;
    }
    if (k < HH) {
        hs[b * HH + k] = hlast;
        cs[b * HH + k] = c;
    }
}

// ---------------- Kernel 3: FC epilogue ----------------
__global__ __launch_bounds__(256) void fc_kernel(
    const float* __restrict__ hs, const float* __restrict__ W_fc,
    const float* __restrict__ b_fc, float* __restrict__ out)
{
    int idx = blockIdx.x * blockDim.x + threadIdx.x;   // 512*10
    if (idx < BB * 10) {
        int b = idx / 10, o = idx % 10;
        float a = b_fc[o];
        #pragma unroll
        for (int kx = 0; kx < HH; ++kx)
            a += hs[b * HH + kx] * W_fc[o * HH + kx];
        out[idx] = a;
    }
}

extern "C" void kernel_launch(void* const* d_in, const int* in_sizes, int n_in,
                              void* d_out, int out_size, void* d_ws, size_t ws_size,
                              hipStream_t stream)
{
    const float* x    = (const float*)d_in[0];
    const float* W_ih = (const float*)d_in[1];
    const float* W_hh = (const float*)d_in[2];
    const float* b_ih = (const float*)d_in[3];
    const float* b_hh = (const float*)d_in[4];
    const float* W_fc = (const float*)d_in[5];
    const float* b_fc = (const float*)d_in[6];
    float* out = (float*)d_out;
    char* wsb = (char*)d_ws;

    const size_t hs_b = (size_t)BB * HH * sizeof(float);        // 102400
    const size_t wfrags_b = (size_t)13 * 4 * 64 * 8 * 2;        // 53248
    const size_t whh_b = (size_t)GG * 56 * 2;                   // 22400
    const size_t bias_b = 1024;
    const size_t fixed_b = 2 * hs_b + wfrags_b + whh_b + bias_b;

    int Tc = TT;
    while (Tc > 64 && (size_t)BB * Tc * GG * 2 + fixed_b > ws_size)
        Tc >>= 1;

    _Float16* xp16 = (_Float16*)wsb;
    char* p = wsb + (size_t)BB * Tc * GG * 2;
    float* hsbuf = (float*)p;            p += hs_b;
    float* csbuf = (float*)p;            p += hs_b;
    _Float16* wfrags = (_Float16*)p;     p += wfrags_b;
    _Float16* whh16 = (_Float16*)p;      p += whh_b;
    float* biasv = (float*)p;

    prep_kernel<<<25, 256, 0, stream>>>(W_ih, W_hh, b_ih, b_hh, wfrags, whh16, biasv);

    const int nch = TT / Tc;
    for (int j = 0; j < nch; ++j) {
        xproj_mfma<<<(BB * Tc) / 64, 256, 0, stream>>>(x, wfrags, xp16, j * Tc, Tc);
        lstm_rec<<<BB, 64, 0, stream>>>(xp16, whh16, biasv, hsbuf, csbuf, Tc, j == 0);
    }
    fc_kernel<<<(BB * 10 + 255) / 256, 256, 0, stream>>>(hsbuf, W_fc, b_fc, out);
}